// Round 2
// baseline (213.533 us; speedup 1.0000x reference)
//
#include <hip/hip_runtime.h>
#include <hip/hip_bf16.h>
#include <math.h>

// Shapes (fixed by the problem)
#define NB 16
#define NA 128
#define HD 256
#define EF 30

// SELU constants
#define SELU_SCALE 1.0507009873554805f
#define SELU_AS    1.7580993408473766f   // scale * alpha

// -----------------------------------------------------------------------------
// Kernel A: fused filter-net + edge reduce.
// One block per (b, i). 256 threads; thread t owns output feature f = t.
//   s[j]   = bf[f] + sum_k e[b,i,j,k] * Wf[f,k]        (k inner, 30 FMAs)
//   ef[j]  = selu(s[j]) * edge_mask[b,i,j]
//   h1[b,i,f] = sum_j h[b,j,f] * ef[j]
// e[b,i,j,k] and edge_mask[b,i,j] are block-uniform -> compiler emits s_load,
// keeping the inner loop pure v_fma with an SGPR operand (no LDS broadcasts).
// -----------------------------------------------------------------------------
__global__ __launch_bounds__(256, 4)
void efconv_filter_edge(const float* __restrict__ e,
                        const float* __restrict__ h,
                        const float* __restrict__ edge_mask,
                        const float* __restrict__ Wf,
                        const float* __restrict__ bf,
                        float* __restrict__ h1)
{
    const int bi = blockIdx.x;          // 0..2047
    const int b  = bi >> 7;             // bi / NA
    const int f  = threadIdx.x;         // 0..255

    // Per-thread filter row (30 VGPRs). One-time load, L1/L2-cached.
    float wf[EF];
#pragma unroll
    for (int k = 0; k < EF; ++k) wf[k] = Wf[f * EF + k];
    const float bff = bf[f];

    const float* __restrict__ e_row  = e + (size_t)bi * (NA * EF);   // uniform
    const float* __restrict__ em_row = edge_mask + (size_t)bi * NA;  // uniform
    const float* __restrict__ hb     = h + (size_t)b * NA * HD + f;  // coalesced

    float acc = 0.0f;
#pragma unroll 4
    for (int j = 0; j < NA; ++j) {
        const float* __restrict__ ej = e_row + j * EF;   // uniform address
        float s = bff;
#pragma unroll
        for (int k = 0; k < EF; ++k) s = fmaf(ej[k], wf[k], s);
        // selu(s) (branchless) * edge_mask
        const float t   = __expf(s);
        const float pos = SELU_SCALE * s;
        const float neg = fmaf(SELU_AS, t, -SELU_AS);
        const float ef_v = (s > 0.0f ? pos : neg) * em_row[j];
        acc = fmaf(hb[(size_t)j * HD], ef_v, acc);
    }
    h1[(size_t)bi * HD + f] = acc;
}

// -----------------------------------------------------------------------------
// Kernel B: gated node MLP + residual.
//   out[bi,f] = selu( sum_c z[bi,c]*Ww[f,c] + bw[f] ) * node_mask[bi] + h[bi,f]
//   z = concat(h, h1) along c (512)
// 8 rows per block (grid = 256). Thread t owns feature f = t for all 8 rows.
// z values are block-uniform -> s_load; each lane streams its own Ww row
// (float4, contiguous per lane, L2-resident: 512 KB total weight).
// -----------------------------------------------------------------------------
#define BROWS 8
__global__ __launch_bounds__(256)
void efconv_node_mlp(const float* __restrict__ h,
                     const float* __restrict__ h1,
                     const float* __restrict__ node_mask,
                     const float* __restrict__ Ww,
                     const float* __restrict__ bw,
                     float* __restrict__ out)
{
    const int f    = threadIdx.x;            // 0..255
    const int row0 = blockIdx.x * BROWS;     // 0..2047 step 8

    float acc[BROWS];
    const float bwf = bw[f];
#pragma unroll
    for (int r = 0; r < BROWS; ++r) acc[r] = bwf;

    const float* __restrict__ wrow = Ww + (size_t)f * (2 * HD);

    // first half of K: z = h
    for (int c = 0; c < HD; c += 4) {
        const float4 w = *(const float4*)(wrow + c);
#pragma unroll
        for (int r = 0; r < BROWS; ++r) {
            const float* __restrict__ zr = h + (size_t)(row0 + r) * HD + c; // uniform
            acc[r] = fmaf(zr[0], w.x, acc[r]);
            acc[r] = fmaf(zr[1], w.y, acc[r]);
            acc[r] = fmaf(zr[2], w.z, acc[r]);
            acc[r] = fmaf(zr[3], w.w, acc[r]);
        }
    }
    // second half of K: z = h1
    for (int c = 0; c < HD; c += 4) {
        const float4 w = *(const float4*)(wrow + HD + c);
#pragma unroll
        for (int r = 0; r < BROWS; ++r) {
            const float* __restrict__ zr = h1 + (size_t)(row0 + r) * HD + c; // uniform
            acc[r] = fmaf(zr[0], w.x, acc[r]);
            acc[r] = fmaf(zr[1], w.y, acc[r]);
            acc[r] = fmaf(zr[2], w.z, acc[r]);
            acc[r] = fmaf(zr[3], w.w, acc[r]);
        }
    }

#pragma unroll
    for (int r = 0; r < BROWS; ++r) {
        const int bi = row0 + r;
        const float nm = node_mask[bi];
        const float s  = acc[r];
        const float t   = __expf(s);
        const float pos = SELU_SCALE * s;
        const float neg = fmaf(SELU_AS, t, -SELU_AS);
        const float v   = (s > 0.0f ? pos : neg);
        out[(size_t)bi * HD + f] = fmaf(v, nm, h[(size_t)bi * HD + f]);
    }
}

// -----------------------------------------------------------------------------
// Launch. Inputs (setup_inputs order): h, e, node_mask, edge_mask, Wf, bf, Ww, bw
// Workspace: h1 intermediate (2048*256 floats = 2 MB).
// -----------------------------------------------------------------------------
extern "C" void kernel_launch(void* const* d_in, const int* in_sizes, int n_in,
                              void* d_out, int out_size, void* d_ws, size_t ws_size,
                              hipStream_t stream)
{
    (void)in_sizes; (void)n_in; (void)out_size; (void)ws_size;
    const float* h  = (const float*)d_in[0];
    const float* e  = (const float*)d_in[1];
    const float* nm = (const float*)d_in[2];
    const float* em = (const float*)d_in[3];
    const float* Wf = (const float*)d_in[4];
    const float* bf = (const float*)d_in[5];
    const float* Ww = (const float*)d_in[6];
    const float* bw = (const float*)d_in[7];
    float* out = (float*)d_out;
    float* h1  = (float*)d_ws;   // 2 MB scratch

    hipLaunchKernelGGL(efconv_filter_edge, dim3(NB * NA), dim3(256), 0, stream,
                       e, h, em, Wf, bf, h1);
    hipLaunchKernelGGL(efconv_node_mlp, dim3(NB * NA / BROWS), dim3(256), 0, stream,
                       h, h1, nm, Ww, bw, out);
}

// Round 4
// 116.426 us; speedup vs baseline: 1.8341x; 1.8341x over previous
//
#include <hip/hip_runtime.h>
#include <hip/hip_bf16.h>

#define NB 16
#define NA 128
#define HD 256
#define EF 30

#define SELU_SCALE 1.0507009873554805f
#define SELU_AS    1.7580993408473766f   // scale * alpha

typedef __attribute__((ext_vector_type(8))) short bf16x8;
typedef __attribute__((ext_vector_type(4))) float f32x4;

__device__ __forceinline__ unsigned short f2u16(float x) {
    union { __hip_bfloat16 b; unsigned short u; } cv;
    cv.b = __float2bfloat16(x);   // RNE
    return cv.u;
}
__device__ __forceinline__ short f2s16(float x) { return (short)f2u16(x); }

__device__ __forceinline__ float selu_f(float s) {
    float pos = SELU_SCALE * s;
    float neg = fmaf(SELU_AS, __expf(s), -SELU_AS);
    return s > 0.f ? pos : neg;
}

// -----------------------------------------------------------------------------
// Prep: pre-swizzle Wf and Ww into MFMA B-fragment order (bf16), so the main
// kernels load B-operands as single coalesced dwordx4 per lane.
// B-frag layout (16x16x32): lane l holds B[k][j] with j = l&15, k = (l>>4)*8+e.
// WfFrag[t][lane][e]    : t = f-tile (16), k-pad 30->32 with zeros.  16 KB
// WwFrag[t][s][lane][e] : t = f-tile (16), s = k-step (16).         256 KB
// -----------------------------------------------------------------------------
__global__ __launch_bounds__(256)
void efconv_prep(const float* __restrict__ Wf, const float* __restrict__ Ww,
                 unsigned short* __restrict__ WfFragU, unsigned short* __restrict__ WwFragU)
{
    const int idx = blockIdx.x * 256 + threadIdx.x;
    if (idx < 16*64*8) {
        const int e = idx & 7, lane = (idx >> 3) & 63, t = idx >> 9;
        const int f = t*16 + (lane & 15);
        const int k = ((lane >> 4) << 3) + e;
        const float v = (k < EF) ? Wf[f*EF + k] : 0.f;
        WfFragU[idx] = f2u16(v);
    }
    const int jdx = idx - 16*64*8;
    if (jdx >= 0 && jdx < 16*16*64*8) {
        const int e = jdx & 7, lane = (jdx >> 3) & 63;
        const int s = (jdx >> 9) & 15, t = jdx >> 13;
        const int f = t*16 + (lane & 15);
        const int k = s*32 + ((lane >> 4) << 3) + e;
        WwFragU[jdx] = f2u16(Ww[f*(2*HD) + k]);
    }
}

// -----------------------------------------------------------------------------
// Stage 1: per (b,i) block (2048 blocks, 4 waves). Wave w owns f-tiles 4w..4w+3.
// For each of 8 j-tiles: A-frag from e (fp32->bf16 on the fly, k padded to 32),
// 4 MFMAs (bias folded into acc init), then fused SELU*edge_mask*h j-reduction
// into 4 per-lane partials. shfl_xor(16,32) finishes the j-sum; h1 stored bf16.
// No LDS, no barriers.
// A-frag: row i = lane&15 (j within tile), k = (lane>>4)*8+e.
// D: col f = lane&15 (within f-tile), row j = jtile + (lane>>4)*4 + r.
// -----------------------------------------------------------------------------
__global__ __launch_bounds__(256)
void efconv_stage1(const float* __restrict__ e, const float* __restrict__ h,
                   const float* __restrict__ em, const float* __restrict__ bf,
                   const bf16x8* __restrict__ WfFrag, unsigned short* __restrict__ h1b)
{
    const int bi  = blockIdx.x;          // (b,i)
    const int b   = bi >> 7;
    const int tid = threadIdx.x;
    const int wid = tid >> 6;
    const int lane = tid & 63;
    const int l15 = lane & 15;
    const int lq  = lane >> 4;
    const int k0  = lq * 8;

    const float* __restrict__ e_row  = e  + (size_t)bi * (NA*EF);
    const float* __restrict__ em_row = em + (size_t)bi * NA;
    const float* __restrict__ hb     = h  + (size_t)b  * (NA*HD);

    bf16x8 Bf[4];
    float bias[4];
#pragma unroll
    for (int n = 0; n < 4; ++n) {
        const int t = wid*4 + n;
        Bf[n]   = WfFrag[t*64 + lane];      // coalesced 16B/lane
        bias[n] = bf[t*16 + l15];
    }

    float partial[4] = {0.f, 0.f, 0.f, 0.f};

    for (int j0 = 0; j0 < NA; j0 += 16) {
        const int j = j0 + l15;
        // A-frag: 8 consecutive k of e[b,i,j,:] (rows are 8B-aligned: 30 floats)
        const float2* __restrict__ ep2 = reinterpret_cast<const float2*>(e_row + j*EF);
        bf16x8 Af;
#pragma unroll
        for (int p = 0; p < 4; ++p) {
            const int kk = k0 + 2*p;
            float2 v;
            if (kk < EF) v = ep2[kk >> 1]; else { v.x = 0.f; v.y = 0.f; }
            Af[2*p]   = f2s16(v.x);
            Af[2*p+1] = f2s16(v.y);
        }
        const int jr = j0 + lq*4;            // first of this lane's 4 D-rows
        float emv[4];
#pragma unroll
        for (int r = 0; r < 4; ++r) emv[r] = em_row[jr + r];

#pragma unroll
        for (int n = 0; n < 4; ++n) {
            f32x4 acc = {bias[n], bias[n], bias[n], bias[n]};
            acc = __builtin_amdgcn_mfma_f32_16x16x32_bf16(Af, Bf[n], acc, 0, 0, 0);
            const int f = (wid*4 + n)*16 + l15;
#pragma unroll
            for (int r = 0; r < 4; ++r) {
                const float efv = selu_f(acc[r]) * emv[r];
                partial[n] = fmaf(hb[(jr + r)*HD + f], efv, partial[n]);
            }
        }
    }
    // finish j-sum: combine the 4 lane-groups holding the same f
#pragma unroll
    for (int n = 0; n < 4; ++n) {
        partial[n] += __shfl_xor(partial[n], 16);
        partial[n] += __shfl_xor(partial[n], 32);
    }
    if (lane < 16) {
#pragma unroll
        for (int n = 0; n < 4; ++n) {
            const int f = (wid*4 + n)*16 + lane;
            h1b[(size_t)bi*HD + f] = f2u16(partial[n]);
        }
    }
}

// -----------------------------------------------------------------------------
// Stage 2: out = selu(concat(h,h1) @ Ww^T + bw) * node_mask + h.
// One wave per (16-row M-tile, 16-col N-tile): 128*16 = 2048 waves = 512 blocks.
// K = 512 = 16 MFMA steps; s<8 reads h (fp32->bf16), s>=8 reads h1 (bf16 direct).
// B-frags coalesced from WwFrag. No LDS, no barriers.
// -----------------------------------------------------------------------------
__global__ __launch_bounds__(256)
void efconv_stage2(const float* __restrict__ h, const unsigned short* __restrict__ h1b,
                   const float* __restrict__ nm, const float* __restrict__ bw,
                   const bf16x8* __restrict__ WwFrag, float* __restrict__ out)
{
    const int tid  = threadIdx.x;
    const int lane = tid & 63;
    const int wid  = tid >> 6;
    const int wgid = blockIdx.x*4 + wid;   // 0..2047
    const int m    = wgid >> 4;            // M-tile 0..127
    const int t    = wgid & 15;            // N-tile 0..15
    const int l15  = lane & 15;
    const int lq   = lane >> 4;
    const int k0   = lq * 8;
    const int row  = m*16 + l15;           // A-operand row (node index)

    const float biasv = bw[t*16 + l15];
    f32x4 acc = {biasv, biasv, biasv, biasv};

    const float4* __restrict__ hrow = reinterpret_cast<const float4*>(h + (size_t)row*HD);
#pragma unroll
    for (int s = 0; s < 8; ++s) {          // z = h  (k < 256)
        const int k = s*32 + k0;
        const float4 v0 = hrow[k >> 2];
        const float4 v1 = hrow[(k >> 2) + 1];
        bf16x8 Af;
        Af[0]=f2s16(v0.x); Af[1]=f2s16(v0.y); Af[2]=f2s16(v0.z); Af[3]=f2s16(v0.w);
        Af[4]=f2s16(v1.x); Af[5]=f2s16(v1.y); Af[6]=f2s16(v1.z); Af[7]=f2s16(v1.w);
        const bf16x8 Bfr = WwFrag[(t*16 + s)*64 + lane];
        acc = __builtin_amdgcn_mfma_f32_16x16x32_bf16(Af, Bfr, acc, 0, 0, 0);
    }
    const bf16x8* __restrict__ h1row = reinterpret_cast<const bf16x8*>(h1b + (size_t)row*HD);
#pragma unroll
    for (int s = 8; s < 16; ++s) {         // z = h1 (k >= 256), already bf16
        const int k = s*32 + k0 - 256;
        const bf16x8 Af = h1row[k >> 3];
        const bf16x8 Bfr = WwFrag[(t*16 + s)*64 + lane];
        acc = __builtin_amdgcn_mfma_f32_16x16x32_bf16(Af, Bfr, acc, 0, 0, 0);
    }

    const int f = t*16 + l15;
#pragma unroll
    for (int r = 0; r < 4; ++r) {
        const int bi = m*16 + lq*4 + r;
        const float v = selu_f(acc[r]);
        out[(size_t)bi*HD + f] = fmaf(v, nm[bi], h[(size_t)bi*HD + f]);
    }
}

// -----------------------------------------------------------------------------
// Launch. Inputs: h, e, node_mask, edge_mask, Wf, bf, Ww, bw.
// ws layout: [0,1MB) h1 bf16 | [1MB,+16KB) WfFrag | [+16KB,+256KB) WwFrag.
// Total 1.27 MB (ws >= 2MB proven in round 2).
// -----------------------------------------------------------------------------
extern "C" void kernel_launch(void* const* d_in, const int* in_sizes, int n_in,
                              void* d_out, int out_size, void* d_ws, size_t ws_size,
                              hipStream_t stream)
{
    (void)in_sizes; (void)n_in; (void)out_size; (void)ws_size;
    const float* h  = (const float*)d_in[0];
    const float* e  = (const float*)d_in[1];
    const float* nm = (const float*)d_in[2];
    const float* em = (const float*)d_in[3];
    const float* Wf = (const float*)d_in[4];
    const float* bf = (const float*)d_in[5];
    const float* Ww = (const float*)d_in[6];
    const float* bw = (const float*)d_in[7];
    float* out = (float*)d_out;

    unsigned short* h1b     = (unsigned short*)d_ws;
    unsigned short* WfFragU = (unsigned short*)((char*)d_ws + (1u << 20));
    unsigned short* WwFragU = (unsigned short*)((char*)d_ws + (1u << 20) + 16384);

    hipLaunchKernelGGL(efconv_prep, dim3(544), dim3(256), 0, stream,
                       Wf, Ww, WfFragU, WwFragU);
    hipLaunchKernelGGL(efconv_stage1, dim3(NB * NA), dim3(256), 0, stream,
                       e, h, em, bf, (const bf16x8*)WfFragU, h1b);
    hipLaunchKernelGGL(efconv_stage2, dim3(512), dim3(256), 0, stream,
                       h, h1b, nm, bw, (const bf16x8*)WwFragU, out);
}